// Round 7
// baseline (106.183 us; speedup 1.0000x reference)
//
#include <hip/hip_runtime.h>
#include <hip/hip_bf16.h>

// Problem constants
#define B_  64
#define N1_ 8
#define KK  128
#define EE  256
#define HH  512
#define BN  (B_ * N1_)   // 512

typedef __attribute__((ext_vector_type(8))) short short8;   // bf16x8 MFMA frag
typedef __attribute__((ext_vector_type(4))) float f32x4;    // MFMA acc

__device__ __forceinline__ short bfs(float f) {
  __hip_bfloat16 h = __float2bfloat16(f);   // RNE
  return __builtin_bit_cast(short, h);
}

__device__ __forceinline__ float tanhf_fast(float x) {
  // tanh(x) = 1 - 2/(exp(2x)+1);  exp(2x) = exp2(2*log2e*x)
  float e2 = __builtin_amdgcn_exp2f(2.8853900817779268f * x);
  return 1.0f - 2.0f * __builtin_amdgcn_rcpf(e2 + 1.0f);
}

// ---------------------------------------------------------------------------
// k_prep: blocks 0..127  -> wk_w f32 -> bf16
//         blocks 128..159 -> qproj MFMA: qp[bn][h] = q.wq[h] + wq_b[h] + wk_b[h]
// qproj reads wq in f32 and converts inline (no cross-block dependency).
// MFMA frag layout [m89]: A row=lane&15, e=(lane>>4)*8+s*32; D col=lane&15,
// row=(lane>>4)*4+reg.
// ---------------------------------------------------------------------------
__global__ __launch_bounds__(256) void k_prep(
    const float* __restrict__ wk_w,
    const float* __restrict__ queries,
    const float* __restrict__ wq_w,
    const float* __restrict__ wq_b,
    const float* __restrict__ wk_b,
    unsigned short* __restrict__ wk_bf,
    float* __restrict__ qp) {
  const int bid = blockIdx.x, t = threadIdx.x;
  if (bid < 128) {
    const int i = (bid * 256 + t) * 4;
    float4 v = *(const float4*)(wk_w + i);
    union { unsigned short u[4]; uint2 p; } pk;
    pk.u[0] = (unsigned short)bfs(v.x);
    pk.u[1] = (unsigned short)bfs(v.y);
    pk.u[2] = (unsigned short)bfs(v.z);
    pk.u[3] = (unsigned short)bfs(v.w);
    *(uint2*)(wk_bf + i) = pk.p;
  } else {
    const int w = t >> 6, l = t & 63, lg = l >> 4, ll = l & 15;
    const int bn0 = (bid - 128) * 16;
    short8 af[8];
    {
      const float* qr = queries + (size_t)(bn0 + ll) * EE + lg * 8;
      #pragma unroll
      for (int s = 0; s < 8; ++s) {
        float4 x = *(const float4*)(qr + s * 32);
        float4 y = *(const float4*)(qr + s * 32 + 4);
        short8 f;
        f[0] = bfs(x.x); f[1] = bfs(x.y); f[2] = bfs(x.z); f[3] = bfs(x.w);
        f[4] = bfs(y.x); f[5] = bfs(y.y); f[6] = bfs(y.z); f[7] = bfs(y.w);
        af[s] = f;
      }
    }
    #pragma unroll
    for (int i = 0; i < 8; ++i) {
      const int h0 = w * 128 + i * 16;
      const float* bp = wq_w + (size_t)(h0 + ll) * EE + lg * 8;
      f32x4 a = {0.f, 0.f, 0.f, 0.f};
      #pragma unroll
      for (int s = 0; s < 8; ++s) {
        float4 x = *(const float4*)(bp + s * 32);
        float4 y = *(const float4*)(bp + s * 32 + 4);
        short8 f;
        f[0] = bfs(x.x); f[1] = bfs(x.y); f[2] = bfs(x.z); f[3] = bfs(x.w);
        f[4] = bfs(y.x); f[5] = bfs(y.y); f[6] = bfs(y.z); f[7] = bfs(y.w);
        a = __builtin_amdgcn_mfma_f32_16x16x32_bf16(af[s], f, a, 0, 0, 0);
      }
      const int h = h0 + ll;
      const float add = wq_b[h] + wk_b[h];
      #pragma unroll
      for (int r = 0; r < 4; ++r)
        qp[(size_t)(bn0 + lg * 4 + r) * HH + h] = a[r] + add;
    }
  }
}

// ---------------------------------------------------------------------------
// k_scores: grid 2048 = 512 bn x 4 row-groups (32 rows). Block 256 thr =
// 4 waves; ALL waves share the same 32 rows; wave w owns h-quarter w*128.
// A staged ONCE in LDS pre-converted to bf16 fragment layout (lane-linear,
// conflict-free). B register-double-buffered straight from L2 wk_bf.
// NO barriers in the main loop -> waves run fully independent.
// Writes partial scores scp[row][quarter] (f32x4 per row).
// ---------------------------------------------------------------------------
__global__ __launch_bounds__(256) void k_scores(
    const float* __restrict__ keys,
    const unsigned short* __restrict__ wk_bf,
    const float* __restrict__ wv_w,
    const float* __restrict__ qp,
    float* __restrict__ scp) {
  const int t = threadIdx.x, w = t >> 6, l = t & 63;
  const int lg = l >> 4, ll = l & 15;
  const int bid = blockIdx.x;
  const int bn = bid >> 2, rg = bid & 3;

  __shared__ __align__(16) short a_sm[2][8][64][8];  // [chain][slot][lane][8] bf16 = 16 KB
  __shared__ float qb_s[HH];
  __shared__ float wv_s[HH];

  qb_s[t]       = qp[(size_t)bn * HH + t];
  qb_s[t + 256] = qp[(size_t)bn * HH + t + 256];
  wv_s[t]       = wv_w[t];
  wv_s[t + 256] = wv_w[t + 256];

  // stage A (32 rows x 256 e) as pre-converted bf16 fragments
  {
    const float* kbase = keys + (size_t)(bn * KK + rg * 32) * EE;
    #pragma unroll
    for (int j = 0; j < 4; ++j) {
      const int c = t + j * 256;            // chunk 0..1023
      const int chain = c >> 9;
      const int slot  = (c >> 6) & 7;
      const int lane  = c & 63;
      const int row   = chain * 16 + (lane & 15);
      const int e     = (lane >> 4) * 8 + slot * 32;
      float4 x = *(const float4*)(kbase + (size_t)row * EE + e);
      float4 y = *(const float4*)(kbase + (size_t)row * EE + e + 4);
      short8 f;
      f[0] = bfs(x.x); f[1] = bfs(x.y); f[2] = bfs(x.z); f[3] = bfs(x.w);
      f[4] = bfs(y.x); f[5] = bfs(y.y); f[6] = bfs(y.z); f[7] = bfs(y.w);
      *(short8*)&a_sm[chain][slot][lane][0] = f;
    }
  }
  __syncthreads();

  short8 af0[8], af1[8];
  #pragma unroll
  for (int s = 0; s < 8; ++s) {
    af0[s] = *(const short8*)&a_sm[0][s][l][0];   // lane-linear: conflict-free
    af1[s] = *(const short8*)&a_sm[1][s][l][0];
  }

  const int q8 = w * 8;                 // first h-tile of this wave's quarter
  float p0[4] = {0.f, 0.f, 0.f, 0.f};
  float p1[4] = {0.f, 0.f, 0.f, 0.f};
  short8 bA[8], bB[8];
  const unsigned short* bbase = wk_bf + (size_t)ll * EE + lg * 8;

#define LOADB(dst, ht) {                                                   \
    const unsigned short* bp = bbase + (size_t)(ht) * 16 * EE;             \
    _Pragma("unroll") for (int s = 0; s < 8; ++s)                          \
      dst[s] = *(const short8*)(bp + s * 32); }

#define STEP(cur, nxt, ii) {                                               \
    if ((ii) < 7) LOADB(nxt, q8 + (ii) + 1);                               \
    f32x4 a0 = {0.f, 0.f, 0.f, 0.f};                                       \
    f32x4 a1 = {0.f, 0.f, 0.f, 0.f};                                       \
    _Pragma("unroll") for (int s = 0; s < 8; ++s) {                        \
      a0 = __builtin_amdgcn_mfma_f32_16x16x32_bf16(af0[s], cur[s], a0, 0, 0, 0); \
      a1 = __builtin_amdgcn_mfma_f32_16x16x32_bf16(af1[s], cur[s], a1, 0, 0, 0); } \
    const int h = (q8 + (ii)) * 16 + ll;                                   \
    const float qb = qb_s[h];                                              \
    const float wv = wv_s[h];                                              \
    _Pragma("unroll") for (int r = 0; r < 4; ++r) {                        \
      p0[r] += wv * tanhf_fast(a0[r] + qb);                                \
      p1[r] += wv * tanhf_fast(a1[r] + qb); } }

  LOADB(bA, q8);
  #pragma unroll
  for (int i = 0; i < 8; i += 2) {
    STEP(bA, bB, i);
    STEP(bB, bA, i + 1);
  }
#undef STEP
#undef LOADB

  // reduce over h within each 16-lane group
  #pragma unroll
  for (int r = 0; r < 4; ++r) {
    #pragma unroll
    for (int off = 1; off <= 8; off <<= 1) {
      p0[r] += __shfl_xor(p0[r], off, 64);
      p1[r] += __shfl_xor(p1[r], off, 64);
    }
  }
  if (ll == 0) {
    float* sp = scp + ((size_t)bn * KK + rg * 32) * 4 + w;   // [row][quarter]
    #pragma unroll
    for (int r = 0; r < 4; ++r) {
      sp[(lg * 4 + r) * 4]        = p0[r];
      sp[(16 + lg * 4 + r) * 4]   = p1[r];
    }
  }
}

// ---------------------------------------------------------------------------
// k_smout: per bn: sum quarter-partials, masked softmax over K=128,
// write attn_weight, then attn_out[bn][e] = sum_k w[k]*keys[bn,k,e].
// ---------------------------------------------------------------------------
__global__ __launch_bounds__(512) void k_smout(
    const float* __restrict__ keys,
    const int* __restrict__ masks,
    const float* __restrict__ scp,
    float* __restrict__ out) {
  const int bn = blockIdx.x;
  const int t  = threadIdx.x;
  __shared__ float sc[KK];
  __shared__ float po[512];
  __shared__ float red[2];

  if (t < KK) {
    float4 s4 = ((const float4*)scp)[(size_t)bn * KK + t];
    sc[t] = s4.x + s4.y + s4.z + s4.w + (float)masks[bn * KK + t] * (-1e9f);
  }
  __syncthreads();
  if (t < 64) {
    float a = fmaxf(sc[t], sc[t + 64]);
    #pragma unroll
    for (int off = 32; off >= 1; off >>= 1) a = fmaxf(a, __shfl_xor(a, off, 64));
    if (t == 0) red[0] = a;
  }
  __syncthreads();
  const float m = red[0];
  if (t < KK) sc[t] = expf(sc[t] - m);
  __syncthreads();
  if (t < 64) {
    float a = sc[t] + sc[t + 64];
    #pragma unroll
    for (int off = 32; off >= 1; off >>= 1) a += __shfl_xor(a, off, 64);
    if (t == 0) red[1] = a;
  }
  __syncthreads();
  const float inv = 1.f / red[1];
  if (t < KK) {
    float wgt = sc[t] * inv;
    sc[t] = wgt;
    out[BN * EE + (size_t)bn * KK + t] = wgt;   // attn_weight
  }
  __syncthreads();

  // weighted sum, k split across thread halves
  const int e = t & 255, kh = t >> 8;
  const float* kb = keys + (size_t)bn * KK * EE + (size_t)kh * 64 * EE;
  float acc = 0.f;
  #pragma unroll 8
  for (int k = 0; k < 64; ++k)
    acc += sc[kh * 64 + k] * kb[k * EE + e];    // coalesced over e
  po[t] = acc;
  __syncthreads();
  if (t < 256) out[(size_t)bn * EE + t] = po[t] + po[t + 256];
}

// ---------------------------------------------------------------------------
extern "C" void kernel_launch(void* const* d_in, const int* in_sizes, int n_in,
                              void* d_out, int out_size, void* d_ws, size_t ws_size,
                              hipStream_t stream) {
  const float* queries = (const float*)d_in[0];
  const float* keys    = (const float*)d_in[1];
  const int*   masks   = (const int*)d_in[2];
  // d_in[3] = num_neg (unused)
  const float* wk_w = (const float*)d_in[4];
  const float* wk_b = (const float*)d_in[5];
  const float* wq_w = (const float*)d_in[6];
  const float* wq_b = (const float*)d_in[7];
  const float* wv_w = (const float*)d_in[8];
  // d_in[9] = wv_b (softmax shift-invariant -> unused)

  float* out = (float*)d_out;
  float* qp  = (float*)d_ws;                                // 512*512 f32 = 1 MB
  unsigned short* wk_bf = (unsigned short*)(qp + BN * HH);  // 256 KB
  float* scp = (float*)(wk_bf + HH * EE);                   // 512*128*4 f32 = 1 MB

  k_prep<<<160, 256, 0, stream>>>(wk_w, queries, wq_w, wq_b, wk_b, wk_bf, qp);
  k_scores<<<BN * 4, 256, 0, stream>>>(keys, wk_bf, wv_w, qp, scp);
  k_smout<<<BN, 512, 0, stream>>>(keys, masks, scp, out);
}

// Round 8
// 86.821 us; speedup vs baseline: 1.2230x; 1.2230x over previous
//
#include <hip/hip_runtime.h>
#include <hip/hip_bf16.h>

// Problem constants
#define B_  64
#define N1_ 8
#define KK  128
#define EE  256
#define HH  512
#define BN  (B_ * N1_)   // 512

typedef __attribute__((ext_vector_type(8))) short short8;   // bf16x8 MFMA frag
typedef __attribute__((ext_vector_type(4))) float f32x4;    // MFMA acc

__device__ __forceinline__ short bfs(float f) {
  __hip_bfloat16 h = __float2bfloat16(f);   // RNE
  return __builtin_bit_cast(short, h);
}

__device__ __forceinline__ float tanhf_fast(float x) {
  // tanh(x) = 1 - 2/(exp(2x)+1);  exp(2x) = exp2(2*log2e*x)
  float e2 = __builtin_amdgcn_exp2f(2.8853900817779268f * x);
  return 1.0f - 2.0f * __builtin_amdgcn_rcpf(e2 + 1.0f);
}

// ---------------------------------------------------------------------------
// k_layout: rewrite wk_w and wq_w (512x256 f32) into FRAGMENT-MAJOR bf16:
//   chunk ((ht*8+s)*64 + lane) [8 elems] = W[ht*16 + (lane&15)][(lane>>4)*8 + s*32 .. +7]
// so a wave's B-fragment load for (h-tile ht, slot s) is one contiguous,
// fully-coalesced 1 KB read: frag[l] = buf[(ht*8+s)*64 + l].
// Reads are coalesced (thread t covers 8 consecutive e); writes scattered 16B.
// ---------------------------------------------------------------------------
__global__ __launch_bounds__(256) void k_layout(
    const float* __restrict__ wk_w, const float* __restrict__ wq_w,
    unsigned short* __restrict__ wk_fr, unsigned short* __restrict__ wq_fr) {
  const int bid = blockIdx.x, t = threadIdx.x;
  const float* src = (bid < 64) ? wk_w : wq_w;
  unsigned short* dst = (bid < 64) ? wk_fr : wq_fr;
  const int g  = (bid & 63) * 256 + t;      // chunk id 0..16383
  const int h  = g >> 5;
  const int e0 = (g & 31) * 8;
  float4 x = *(const float4*)(src + (size_t)h * EE + e0);
  float4 y = *(const float4*)(src + (size_t)h * EE + e0 + 4);
  short8 f;
  f[0] = bfs(x.x); f[1] = bfs(x.y); f[2] = bfs(x.z); f[3] = bfs(x.w);
  f[4] = bfs(y.x); f[5] = bfs(y.y); f[6] = bfs(y.z); f[7] = bfs(y.w);
  const int ht = h >> 4, hl = h & 15;
  const int s = e0 >> 5, lg = (e0 >> 3) & 3;
  const int chunk = (ht * 8 + s) * 64 + lg * 16 + hl;
  *(short8*)(dst + (size_t)chunk * 8) = f;
}

// ---------------------------------------------------------------------------
// k_qproj (MFMA): qp[bn][h] = dot(queries[bn,:], wq[h,:]) + wq_b[h] + wk_b[h]
// 32 blocks x 4 waves; block = 16 bn-rows, wave w = h-range [w*128, +128).
// B from fragment-major wq_fr (coalesced). A inline-converted from queries.
// MFMA frag [m89]: A row=lane&15, e=(lane>>4)*8+s*32; D col=lane&15,
// row=(lane>>4)*4+reg.
// ---------------------------------------------------------------------------
__global__ __launch_bounds__(256) void k_qproj(
    const float* __restrict__ queries,
    const unsigned short* __restrict__ wq_fr,
    const float* __restrict__ wq_b,
    const float* __restrict__ wk_b,
    float* __restrict__ qp) {
  const int t = threadIdx.x, w = t >> 6, l = t & 63;
  const int lg = l >> 4, ll = l & 15;
  const int bn0 = blockIdx.x * 16;
  const short8* wqf = (const short8*)wq_fr;

  short8 af[8];
  {
    const float* qr = queries + (size_t)(bn0 + ll) * EE + lg * 8;
    #pragma unroll
    for (int s = 0; s < 8; ++s) {
      float4 x = *(const float4*)(qr + s * 32);
      float4 y = *(const float4*)(qr + s * 32 + 4);
      short8 f;
      f[0] = bfs(x.x); f[1] = bfs(x.y); f[2] = bfs(x.z); f[3] = bfs(x.w);
      f[4] = bfs(y.x); f[5] = bfs(y.y); f[6] = bfs(y.z); f[7] = bfs(y.w);
      af[s] = f;
    }
  }
  #pragma unroll
  for (int i = 0; i < 8; ++i) {
    const int ht = w * 8 + i;
    f32x4 a = {0.f, 0.f, 0.f, 0.f};
    #pragma unroll
    for (int s = 0; s < 8; ++s) {
      short8 bfr = wqf[(ht * 8 + s) * 64 + l];
      a = __builtin_amdgcn_mfma_f32_16x16x32_bf16(af[s], bfr, a, 0, 0, 0);
    }
    const int h = ht * 16 + ll;
    const float add = wq_b[h] + wk_b[h];
    #pragma unroll
    for (int r = 0; r < 4; ++r)
      qp[(size_t)(bn0 + lg * 4 + r) * HH + h] = a[r] + add;
  }
}

// ---------------------------------------------------------------------------
// k_scores: grid 2048 = 512 bn x 4 row-groups (32 rows). Block 256 thr =
// 4 waves sharing the same 32 rows; wave w owns h-quarter w*128.
// A staged once in LDS pre-converted to fragment layout (lane-linear,
// conflict-free). B register-double-buffered from FRAGMENT-MAJOR wk_fr
// (contiguous 1 KB wave-loads, L2-resident). No barriers in the main loop.
// Writes partial scores scp[row][quarter].
// ---------------------------------------------------------------------------
__global__ __launch_bounds__(256) void k_scores(
    const float* __restrict__ keys,
    const unsigned short* __restrict__ wk_fr,
    const float* __restrict__ wv_w,
    const float* __restrict__ qp,
    float* __restrict__ scp) {
  const int t = threadIdx.x, w = t >> 6, l = t & 63;
  const int lg = l >> 4, ll = l & 15;
  const int bid = blockIdx.x;
  const int bn = bid >> 2, rg = bid & 3;
  const short8* wkf = (const short8*)wk_fr;

  __shared__ __align__(16) short a_sm[2][8][64][8];  // 16 KB
  __shared__ float qb_s[HH];
  __shared__ float wv_s[HH];

  qb_s[t]       = qp[(size_t)bn * HH + t];
  qb_s[t + 256] = qp[(size_t)bn * HH + t + 256];
  wv_s[t]       = wv_w[t];
  wv_s[t + 256] = wv_w[t + 256];

  // stage A (32 rows x 256 e) as pre-converted bf16 fragments
  {
    const float* kbase = keys + (size_t)(bn * KK + rg * 32) * EE;
    #pragma unroll
    for (int j = 0; j < 4; ++j) {
      const int c = t + j * 256;            // chunk 0..1023
      const int chain = c >> 9;
      const int slot  = (c >> 6) & 7;
      const int lane  = c & 63;
      const int row   = chain * 16 + (lane & 15);
      const int e     = (lane >> 4) * 8 + slot * 32;
      float4 x = *(const float4*)(kbase + (size_t)row * EE + e);
      float4 y = *(const float4*)(kbase + (size_t)row * EE + e + 4);
      short8 f;
      f[0] = bfs(x.x); f[1] = bfs(x.y); f[2] = bfs(x.z); f[3] = bfs(x.w);
      f[4] = bfs(y.x); f[5] = bfs(y.y); f[6] = bfs(y.z); f[7] = bfs(y.w);
      *(short8*)&a_sm[chain][slot][lane][0] = f;
    }
  }
  __syncthreads();

  short8 af0[8], af1[8];
  #pragma unroll
  for (int s = 0; s < 8; ++s) {
    af0[s] = *(const short8*)&a_sm[0][s][l][0];   // lane-linear: conflict-free
    af1[s] = *(const short8*)&a_sm[1][s][l][0];
  }

  const int q8 = w * 8;                 // first h-tile of this wave's quarter
  float p0[4] = {0.f, 0.f, 0.f, 0.f};
  float p1[4] = {0.f, 0.f, 0.f, 0.f};
  short8 bA[8], bB[8];

#define LOADB(dst, ht) {                                                   \
    _Pragma("unroll") for (int s = 0; s < 8; ++s)                          \
      dst[s] = wkf[((ht) * 8 + s) * 64 + l]; }

#define STEP(cur, nxt, ii) {                                               \
    if ((ii) < 7) LOADB(nxt, q8 + (ii) + 1);                               \
    f32x4 a0 = {0.f, 0.f, 0.f, 0.f};                                       \
    f32x4 a1 = {0.f, 0.f, 0.f, 0.f};                                       \
    _Pragma("unroll") for (int s = 0; s < 8; ++s) {                        \
      a0 = __builtin_amdgcn_mfma_f32_16x16x32_bf16(af0[s], cur[s], a0, 0, 0, 0); \
      a1 = __builtin_amdgcn_mfma_f32_16x16x32_bf16(af1[s], cur[s], a1, 0, 0, 0); } \
    const int h = (q8 + (ii)) * 16 + ll;                                   \
    const float qb = qb_s[h];                                              \
    const float wv = wv_s[h];                                              \
    _Pragma("unroll") for (int r = 0; r < 4; ++r) {                        \
      p0[r] += wv * tanhf_fast(a0[r] + qb);                                \
      p1[r] += wv * tanhf_fast(a1[r] + qb); } }

  LOADB(bA, q8);
  #pragma unroll
  for (int i = 0; i < 8; i += 2) {
    STEP(bA, bB, i);
    STEP(bB, bA, i + 1);
  }
#undef STEP
#undef LOADB

  // reduce over h within each 16-lane group
  #pragma unroll
  for (int r = 0; r < 4; ++r) {
    #pragma unroll
    for (int off = 1; off <= 8; off <<= 1) {
      p0[r] += __shfl_xor(p0[r], off, 64);
      p1[r] += __shfl_xor(p1[r], off, 64);
    }
  }
  if (ll == 0) {
    float* sp = scp + ((size_t)bn * KK + rg * 32) * 4 + w;   // [row][quarter]
    #pragma unroll
    for (int r = 0; r < 4; ++r) {
      sp[(lg * 4 + r) * 4]      = p0[r];
      sp[(16 + lg * 4 + r) * 4] = p1[r];
    }
  }
}

// ---------------------------------------------------------------------------
// k_smout: per bn: sum quarter-partials, masked softmax over K=128,
// write attn_weight, then attn_out[bn][e] = sum_k w[k]*keys[bn,k,e].
// ---------------------------------------------------------------------------
__global__ __launch_bounds__(512) void k_smout(
    const float* __restrict__ keys,
    const int* __restrict__ masks,
    const float* __restrict__ scp,
    float* __restrict__ out) {
  const int bn = blockIdx.x;
  const int t  = threadIdx.x;
  __shared__ float sc[KK];
  __shared__ float po[512];
  __shared__ float red[2];

  if (t < KK) {
    float4 s4 = ((const float4*)scp)[(size_t)bn * KK + t];
    sc[t] = s4.x + s4.y + s4.z + s4.w + (float)masks[bn * KK + t] * (-1e9f);
  }
  __syncthreads();
  if (t < 64) {
    float a = fmaxf(sc[t], sc[t + 64]);
    #pragma unroll
    for (int off = 32; off >= 1; off >>= 1) a = fmaxf(a, __shfl_xor(a, off, 64));
    if (t == 0) red[0] = a;
  }
  __syncthreads();
  const float m = red[0];
  if (t < KK) sc[t] = expf(sc[t] - m);
  __syncthreads();
  if (t < 64) {
    float a = sc[t] + sc[t + 64];
    #pragma unroll
    for (int off = 32; off >= 1; off >>= 1) a += __shfl_xor(a, off, 64);
    if (t == 0) red[1] = a;
  }
  __syncthreads();
  const float inv = 1.f / red[1];
  if (t < KK) {
    float wgt = sc[t] * inv;
    sc[t] = wgt;
    out[BN * EE + (size_t)bn * KK + t] = wgt;   // attn_weight
  }
  __syncthreads();

  // weighted sum, k split across thread halves
  const int e = t & 255, kh = t >> 8;
  const float* kb = keys + (size_t)bn * KK * EE + (size_t)kh * 64 * EE;
  float acc = 0.f;
  #pragma unroll 8
  for (int k = 0; k < 64; ++k)
    acc += sc[kh * 64 + k] * kb[k * EE + e];    // coalesced over e
  po[t] = acc;
  __syncthreads();
  if (t < 256) out[(size_t)bn * EE + t] = po[t] + po[t + 256];
}

// ---------------------------------------------------------------------------
extern "C" void kernel_launch(void* const* d_in, const int* in_sizes, int n_in,
                              void* d_out, int out_size, void* d_ws, size_t ws_size,
                              hipStream_t stream) {
  const float* queries = (const float*)d_in[0];
  const float* keys    = (const float*)d_in[1];
  const int*   masks   = (const int*)d_in[2];
  // d_in[3] = num_neg (unused)
  const float* wk_w = (const float*)d_in[4];
  const float* wk_b = (const float*)d_in[5];
  const float* wq_w = (const float*)d_in[6];
  const float* wq_b = (const float*)d_in[7];
  const float* wv_w = (const float*)d_in[8];
  // d_in[9] = wv_b (softmax shift-invariant -> unused)

  float* out = (float*)d_out;
  float* qp  = (float*)d_ws;                                // 512*512 f32 = 1 MB
  unsigned short* wk_fr = (unsigned short*)(qp + BN * HH);  // 256 KB
  unsigned short* wq_fr = wk_fr + HH * EE;                  // 256 KB
  float* scp = (float*)(wq_fr + HH * EE);                   // 512*128*4 f32 = 1 MB

  k_layout<<<128, 256, 0, stream>>>(wk_w, wq_w, wk_fr, wq_fr);
  k_qproj<<<32, 256, 0, stream>>>(queries, wq_fr, wq_b, wk_b, qp);
  k_scores<<<BN * 4, 256, 0, stream>>>(keys, wk_fr, wv_w, qp, scp);
  k_smout<<<BN, 512, 0, stream>>>(keys, masks, scp, out);
}

// Round 9
// 65.184 us; speedup vs baseline: 1.6290x; 1.3319x over previous
//
#include <hip/hip_runtime.h>
#include <hip/hip_bf16.h>

// Problem constants
#define B_  64
#define N1_ 8
#define KK  128
#define EE  256
#define HH  512
#define BN  (B_ * N1_)   // 512

typedef __attribute__((ext_vector_type(8))) short short8;   // bf16x8 MFMA frag
typedef __attribute__((ext_vector_type(4))) float f32x4;    // MFMA acc

__device__ __forceinline__ short bfs(float f) {
  __hip_bfloat16 h = __float2bfloat16(f);   // RNE
  return __builtin_bit_cast(short, h);
}

__device__ __forceinline__ float tanhf_fast(float x) {
  // tanh(x) = 1 - 2/(exp(2x)+1);  exp(2x) = exp2(2*log2e*x)
  float e2 = __builtin_amdgcn_exp2f(2.8853900817779268f * x);
  return 1.0f - 2.0f * __builtin_amdgcn_rcpf(e2 + 1.0f);
}

// ---------------------------------------------------------------------------
// k_prep:
//  blocks 0..63  -> rewrite wk_w (512x256 f32) into FRAGMENT-MAJOR bf16:
//     chunk ((ht*8+s)*64 + lane)[8] = wk[ht*16 + (lane&15)][(lane>>4)*8 + s*32 ..]
//     so a wave's B-fragment load is one contiguous coalesced 1 KB read.
//  blocks 64..95 -> qproj MFMA: qp[bn][h] = q.wq[h] + wq_b[h] + wk_b[h]
//     (B read from f32 wq_w inline-converted; no cross-block dependency)
// MFMA frag [m89]: A row=lane&15, e=(lane>>4)*8+s*32; D col=lane&15,
// row=(lane>>4)*4+reg.
// ---------------------------------------------------------------------------
__global__ __launch_bounds__(256) void k_prep(
    const float* __restrict__ wk_w,
    const float* __restrict__ queries,
    const float* __restrict__ wq_w,
    const float* __restrict__ wq_b,
    const float* __restrict__ wk_b,
    unsigned short* __restrict__ wk_fr,
    float* __restrict__ qp) {
  const int bid = blockIdx.x, t = threadIdx.x;
  if (bid < 64) {
    const int g  = bid * 256 + t;           // chunk id 0..16383
    const int h  = g >> 5;
    const int e0 = (g & 31) * 8;
    float4 x = *(const float4*)(wk_w + (size_t)h * EE + e0);
    float4 y = *(const float4*)(wk_w + (size_t)h * EE + e0 + 4);
    short8 f;
    f[0] = bfs(x.x); f[1] = bfs(x.y); f[2] = bfs(x.z); f[3] = bfs(x.w);
    f[4] = bfs(y.x); f[5] = bfs(y.y); f[6] = bfs(y.z); f[7] = bfs(y.w);
    const int ht = h >> 4, hl = h & 15;
    const int s = e0 >> 5, lg = (e0 >> 3) & 3;
    const int chunk = (ht * 8 + s) * 64 + lg * 16 + hl;
    *(short8*)(wk_fr + (size_t)chunk * 8) = f;
  } else {
    const int w = t >> 6, l = t & 63, lg = l >> 4, ll = l & 15;
    const int bn0 = (bid - 64) * 16;
    short8 af[8];
    {
      const float* qr = queries + (size_t)(bn0 + ll) * EE + lg * 8;
      #pragma unroll
      for (int s = 0; s < 8; ++s) {
        float4 x = *(const float4*)(qr + s * 32);
        float4 y = *(const float4*)(qr + s * 32 + 4);
        short8 f;
        f[0] = bfs(x.x); f[1] = bfs(x.y); f[2] = bfs(x.z); f[3] = bfs(x.w);
        f[4] = bfs(y.x); f[5] = bfs(y.y); f[6] = bfs(y.z); f[7] = bfs(y.w);
        af[s] = f;
      }
    }
    #pragma unroll
    for (int i = 0; i < 8; ++i) {
      const int h0 = w * 128 + i * 16;
      const float* bp = wq_w + (size_t)(h0 + ll) * EE + lg * 8;
      f32x4 a = {0.f, 0.f, 0.f, 0.f};
      #pragma unroll
      for (int s = 0; s < 8; ++s) {
        float4 x = *(const float4*)(bp + s * 32);
        float4 y = *(const float4*)(bp + s * 32 + 4);
        short8 f;
        f[0] = bfs(x.x); f[1] = bfs(x.y); f[2] = bfs(x.z); f[3] = bfs(x.w);
        f[4] = bfs(y.x); f[5] = bfs(y.y); f[6] = bfs(y.z); f[7] = bfs(y.w);
        a = __builtin_amdgcn_mfma_f32_16x16x32_bf16(af[s], f, a, 0, 0, 0);
      }
      const int h = h0 + ll;
      const float add = wq_b[h] + wk_b[h];
      #pragma unroll
      for (int r = 0; r < 4; ++r)
        qp[(size_t)(bn0 + lg * 4 + r) * HH + h] = a[r] + add;
    }
  }
}

// ---------------------------------------------------------------------------
// k_fused: one block = one bn (128 key-rows). 4 waves x 32 rows (2 MFMA
// chains each); EVERY wave covers all 512 h -> complete scores per wave,
// so softmax + attn_out fuse in-block. B register-double-buffered from
// fragment-major wk_fr: all 4 waves stream the SAME 1 KB-per-frag sequence
// -> L1 (32 KB) serves the reuse. NO barriers in the main loop.
// B L2 traffic: 512 blocks x 256 KB = 128 MB (~4 us). Keys L3-resident.
// MFMA 16x16x32 C/D: col(h)=lane&15, row(key)=(lane>>4)*4+reg   [m89].
// ---------------------------------------------------------------------------
__global__ __launch_bounds__(256, 2) void k_fused(
    const float* __restrict__ keys,
    const unsigned short* __restrict__ wk_fr,
    const float* __restrict__ wv_w,
    const float* __restrict__ qp,
    const int* __restrict__ masks,
    float* __restrict__ out) {
  const int t  = threadIdx.x;
  const int w  = t >> 6;      // wave 0..3
  const int l  = t & 63;
  const int lg = l >> 4;      // lane group 0..3
  const int ll = l & 15;
  const int bn = blockIdx.x;
  const short8* wkf = (const short8*)wk_fr;

  __shared__ float qb_s[HH];
  __shared__ float wv_s[HH];
  __shared__ float sc[KK];
  __shared__ float red[2];

  qb_s[t]       = qp[(size_t)bn * HH + t];
  qb_s[t + 256] = qp[(size_t)bn * HH + t + 256];
  wv_s[t]       = wv_w[t];
  wv_s[t + 256] = wv_w[t + 256];

  // this wave's 32 rows -> bf16 A-frags in regs (2 chains x 8 slots)
  short8 af0[8], af1[8];
  {
    const float* kp0 = keys + (size_t)(bn * KK + w * 32 + ll) * EE + lg * 8;
    const float* kp1 = kp0 + 16 * EE;
    #pragma unroll
    for (int s = 0; s < 8; ++s) {
      float4 x = *(const float4*)(kp0 + s * 32);
      float4 y = *(const float4*)(kp0 + s * 32 + 4);
      short8 f;
      f[0] = bfs(x.x); f[1] = bfs(x.y); f[2] = bfs(x.z); f[3] = bfs(x.w);
      f[4] = bfs(y.x); f[5] = bfs(y.y); f[6] = bfs(y.z); f[7] = bfs(y.w);
      af0[s] = f;
      x = *(const float4*)(kp1 + s * 32);
      y = *(const float4*)(kp1 + s * 32 + 4);
      f[0] = bfs(x.x); f[1] = bfs(x.y); f[2] = bfs(x.z); f[3] = bfs(x.w);
      f[4] = bfs(y.x); f[5] = bfs(y.y); f[6] = bfs(y.z); f[7] = bfs(y.w);
      af1[s] = f;
    }
  }
  __syncthreads();   // qb_s / wv_s ready

  float p0[4] = {0.f, 0.f, 0.f, 0.f};
  float p1[4] = {0.f, 0.f, 0.f, 0.f};
  short8 bA[8], bB[8];

#define LOADB(dst, ht) {                                                   \
    _Pragma("unroll") for (int s = 0; s < 8; ++s)                          \
      dst[s] = wkf[((ht) * 8 + s) * 64 + l]; }

#define STEP(cur, nxt, ii) {                                               \
    if ((ii) < 31) LOADB(nxt, (ii) + 1);                                   \
    f32x4 a0 = {0.f, 0.f, 0.f, 0.f};                                       \
    f32x4 a1 = {0.f, 0.f, 0.f, 0.f};                                       \
    _Pragma("unroll") for (int s = 0; s < 8; ++s) {                        \
      a0 = __builtin_amdgcn_mfma_f32_16x16x32_bf16(af0[s], cur[s], a0, 0, 0, 0); \
      a1 = __builtin_amdgcn_mfma_f32_16x16x32_bf16(af1[s], cur[s], a1, 0, 0, 0); } \
    const int h = (ii) * 16 + ll;                                          \
    const float qb = qb_s[h];                                              \
    const float wv = wv_s[h];                                              \
    _Pragma("unroll") for (int r = 0; r < 4; ++r) {                        \
      p0[r] += wv * tanhf_fast(a0[r] + qb);                                \
      p1[r] += wv * tanhf_fast(a1[r] + qb); } }

  LOADB(bA, 0);
  #pragma unroll 2
  for (int i = 0; i < 32; i += 2) {
    STEP(bA, bB, i);
    STEP(bB, bA, i + 1);
  }
#undef STEP
#undef LOADB

  // reduce over h within each 16-lane group (col dim of C/D)
  #pragma unroll
  for (int r = 0; r < 4; ++r) {
    #pragma unroll
    for (int off = 1; off <= 8; off <<= 1) {
      p0[r] += __shfl_xor(p0[r], off, 64);
      p1[r] += __shfl_xor(p1[r], off, 64);
    }
  }
  if (ll == 0) {
    #pragma unroll
    for (int r = 0; r < 4; ++r) {
      sc[w * 32 + lg * 4 + r]      = p0[r];
      sc[w * 32 + 16 + lg * 4 + r] = p1[r];
    }
  }
  __syncthreads();

  // masked softmax over K=128 (wv_b omitted: softmax shift-invariant)
  if (t < KK) sc[t] += (float)masks[bn * KK + t] * (-1e9f);
  __syncthreads();
  if (t < 64) {
    float a = fmaxf(sc[t], sc[t + 64]);
    #pragma unroll
    for (int off = 32; off >= 1; off >>= 1) a = fmaxf(a, __shfl_xor(a, off, 64));
    if (t == 0) red[0] = a;
  }
  __syncthreads();
  const float m = red[0];
  if (t < KK) sc[t] = expf(sc[t] - m);
  __syncthreads();
  if (t < 64) {
    float a = sc[t] + sc[t + 64];
    #pragma unroll
    for (int off = 32; off >= 1; off >>= 1) a += __shfl_xor(a, off, 64);
    if (t == 0) red[1] = a;
  }
  __syncthreads();
  const float inv = 1.f / red[1];
  if (t < KK) {
    float wgt = sc[t] * inv;
    sc[t] = wgt;
    out[BN * EE + (size_t)bn * KK + t] = wgt;   // attn_weight
  }
  __syncthreads();

  // attn_out[bn][e=t] = sum_k w[k] * keys[bn,k,e]  (f32 keys, coalesced)
  const float* kb = keys + (size_t)bn * KK * EE;
  float acc = 0.f;
  #pragma unroll 8
  for (int k = 0; k < KK; ++k)
    acc += sc[k] * kb[k * EE + t];
  out[(size_t)bn * EE + t] = acc;
}

// ---------------------------------------------------------------------------
extern "C" void kernel_launch(void* const* d_in, const int* in_sizes, int n_in,
                              void* d_out, int out_size, void* d_ws, size_t ws_size,
                              hipStream_t stream) {
  const float* queries = (const float*)d_in[0];
  const float* keys    = (const float*)d_in[1];
  const int*   masks   = (const int*)d_in[2];
  // d_in[3] = num_neg (unused)
  const float* wk_w = (const float*)d_in[4];
  const float* wk_b = (const float*)d_in[5];
  const float* wq_w = (const float*)d_in[6];
  const float* wq_b = (const float*)d_in[7];
  const float* wv_w = (const float*)d_in[8];
  // d_in[9] = wv_b (softmax shift-invariant -> unused)

  float* out = (float*)d_out;
  float* qp  = (float*)d_ws;                                // 512*512 f32 = 1 MB
  unsigned short* wk_fr = (unsigned short*)(qp + BN * HH);  // 256 KB

  k_prep<<<96, 256, 0, stream>>>(wk_w, queries, wq_w, wq_b, wk_b, wk_fr, qp);
  k_fused<<<BN, 256, 0, stream>>>(keys, wk_fr, wv_w, qp, masks, out);
}

// Round 10
// 57.167 us; speedup vs baseline: 1.8574x; 1.1402x over previous
//
#include <hip/hip_runtime.h>
#include <hip/hip_bf16.h>

// Problem constants
#define B_  64
#define N1_ 8
#define KK  128
#define EE  256
#define HH  512
#define BN  (B_ * N1_)   // 512

typedef __attribute__((ext_vector_type(8))) short short8;   // bf16x8 MFMA frag
typedef __attribute__((ext_vector_type(4))) float f32x4;    // MFMA acc

__device__ __forceinline__ short bfs(float f) {
  __hip_bfloat16 h = __float2bfloat16(f);   // RNE
  return __builtin_bit_cast(short, h);
}

__device__ __forceinline__ float tanhf_fast(float x) {
  // tanh(x) = 1 - 2/(exp(2x)+1);  exp(2x) = exp2(2*log2e*x)
  float e2 = __builtin_amdgcn_exp2f(2.8853900817779268f * x);
  return 1.0f - 2.0f * __builtin_amdgcn_rcpf(e2 + 1.0f);
}

// async global->LDS, 16 B per lane; LDS dest = wave-uniform base + lane*16
__device__ __forceinline__ void gload16(const void* g, void* l) {
  __builtin_amdgcn_global_load_lds(
      (const __attribute__((address_space(1))) void*)g,
      (__attribute__((address_space(3))) void*)l, 16, 0, 0);
}

// ---------------------------------------------------------------------------
// k_prep:
//  blocks 0..63  -> rewrite wk_w (512x256 f32) into FRAGMENT-MAJOR bf16:
//     chunk ((ht*8+s)*64 + lane)[8] = wk[ht*16+(lane&15)][(lane>>4)*8+s*32 ..]
//  blocks 64..127 -> qproj MFMA (32 bn-groups x 2 h-halves):
//     qp[bn][h] = q.wq[h] + wq_b[h] + wk_b[h]
// MFMA frag [m89]: A row=lane&15, e=(lane>>4)*8+s*32; D col=lane&15,
// row=(lane>>4)*4+reg.
// ---------------------------------------------------------------------------
__global__ __launch_bounds__(256) void k_prep(
    const float* __restrict__ wk_w,
    const float* __restrict__ queries,
    const float* __restrict__ wq_w,
    const float* __restrict__ wq_b,
    const float* __restrict__ wk_b,
    unsigned short* __restrict__ wk_fr,
    float* __restrict__ qp) {
  const int bid = blockIdx.x, t = threadIdx.x;
  if (bid < 64) {
    const int g  = bid * 256 + t;           // chunk id 0..16383
    const int h  = g >> 5;
    const int e0 = (g & 31) * 8;
    float4 x = *(const float4*)(wk_w + (size_t)h * EE + e0);
    float4 y = *(const float4*)(wk_w + (size_t)h * EE + e0 + 4);
    short8 f;
    f[0] = bfs(x.x); f[1] = bfs(x.y); f[2] = bfs(x.z); f[3] = bfs(x.w);
    f[4] = bfs(y.x); f[5] = bfs(y.y); f[6] = bfs(y.z); f[7] = bfs(y.w);
    const int ht = h >> 4, hl = h & 15;
    const int s = e0 >> 5, lg = (e0 >> 3) & 3;
    const int chunk = (ht * 8 + s) * 64 + lg * 16 + hl;
    *(short8*)(wk_fr + (size_t)chunk * 8) = f;
  } else {
    const int w = t >> 6, l = t & 63, lg = l >> 4, ll = l & 15;
    const int g2 = bid - 64;                // 0..63
    const int bn0 = (g2 >> 1) * 16;         // 32 bn-groups
    const int ht0 = (g2 & 1) * 16;          // h-half (16 h-tiles)
    short8 af[8];
    {
      const float* qr = queries + (size_t)(bn0 + ll) * EE + lg * 8;
      #pragma unroll
      for (int s = 0; s < 8; ++s) {
        float4 x = *(const float4*)(qr + s * 32);
        float4 y = *(const float4*)(qr + s * 32 + 4);
        short8 f;
        f[0] = bfs(x.x); f[1] = bfs(x.y); f[2] = bfs(x.z); f[3] = bfs(x.w);
        f[4] = bfs(y.x); f[5] = bfs(y.y); f[6] = bfs(y.z); f[7] = bfs(y.w);
        af[s] = f;
      }
    }
    #pragma unroll
    for (int i = 0; i < 4; ++i) {
      const int ht = ht0 + w * 4 + i;
      const float* bp = wq_w + (size_t)(ht * 16 + ll) * EE + lg * 8;
      f32x4 a = {0.f, 0.f, 0.f, 0.f};
      #pragma unroll
      for (int s = 0; s < 8; ++s) {
        float4 x = *(const float4*)(bp + s * 32);
        float4 y = *(const float4*)(bp + s * 32 + 4);
        short8 f;
        f[0] = bfs(x.x); f[1] = bfs(x.y); f[2] = bfs(x.z); f[3] = bfs(x.w);
        f[4] = bfs(y.x); f[5] = bfs(y.y); f[6] = bfs(y.z); f[7] = bfs(y.w);
        a = __builtin_amdgcn_mfma_f32_16x16x32_bf16(af[s], f, a, 0, 0, 0);
      }
      const int h = ht * 16 + ll;
      const float add = wq_b[h] + wk_b[h];
      #pragma unroll
      for (int r = 0; r < 4; ++r)
        qp[(size_t)(bn0 + lg * 4 + r) * HH + h] = a[r] + add;
    }
  }
}

// ---------------------------------------------------------------------------
// k_fused: one block = one bn (128 key-rows). 4 waves x 32 rows (2 chains);
// every wave covers all 512 h -> scores complete per wave; softmax + PV fused.
// B path: fragment-major wk_fr staged into LDS via global_load_lds (async,
// un-sinkable issue point), double-buffered, 2-phase: stage(i+1) -> ds_read/
// MFMA/tanh(i) -> barrier (barrier drains vmcnt). LDS layout is linear in
// lane-read order (m104-compliant); ds_reads contiguous 1KB/wave, no conflicts.
// MFMA 16x16x32 C/D: col(h)=lane&15, row(key)=(lane>>4)*4+reg   [m89].
// ---------------------------------------------------------------------------
__global__ __launch_bounds__(256, 2) void k_fused(
    const float* __restrict__ keys,
    const unsigned short* __restrict__ wk_fr,
    const float* __restrict__ wv_w,
    const float* __restrict__ qp,
    const int* __restrict__ masks,
    float* __restrict__ out) {
  const int t  = threadIdx.x;
  const int w  = t >> 6;      // wave 0..3
  const int l  = t & 63;
  const int lg = l >> 4;      // lane group 0..3
  const int ll = l & 15;
  const int bn = blockIdx.x;

  __shared__ __align__(16) char bsm[2][8192];   // B tile double buffer
  __shared__ float qb_s[HH];
  __shared__ float wv_s[HH];
  __shared__ float sc[KK];
  __shared__ float red[2];
  __shared__ float4 po4[4][64];

  qb_s[t]       = qp[(size_t)bn * HH + t];
  qb_s[t + 256] = qp[(size_t)bn * HH + t + 256];
  wv_s[t]       = wv_w[t];
  wv_s[t + 256] = wv_w[t + 256];

  const char* wkb = (const char*)wk_fr;         // 32 tiles x 8192 B
  // stage tile 0 into buf 0 (thread t covers chunks t and t+256)
  gload16(wkb + (size_t)t * 16,        &bsm[0][w * 1024]);
  gload16(wkb + 4096 + (size_t)t * 16, &bsm[0][4096 + w * 1024]);

  // this wave's 32 rows -> bf16 A-frags in regs (2 chains x 8 slots)
  short8 af0[8], af1[8];
  {
    const float* kp0 = keys + (size_t)(bn * KK + w * 32 + ll) * EE + lg * 8;
    const float* kp1 = kp0 + 16 * EE;
    #pragma unroll
    for (int s = 0; s < 8; ++s) {
      float4 x = *(const float4*)(kp0 + s * 32);
      float4 y = *(const float4*)(kp0 + s * 32 + 4);
      short8 f;
      f[0] = bfs(x.x); f[1] = bfs(x.y); f[2] = bfs(x.z); f[3] = bfs(x.w);
      f[4] = bfs(y.x); f[5] = bfs(y.y); f[6] = bfs(y.z); f[7] = bfs(y.w);
      af0[s] = f;
      x = *(const float4*)(kp1 + s * 32);
      y = *(const float4*)(kp1 + s * 32 + 4);
      f[0] = bfs(x.x); f[1] = bfs(x.y); f[2] = bfs(x.z); f[3] = bfs(x.w);
      f[4] = bfs(y.x); f[5] = bfs(y.y); f[6] = bfs(y.z); f[7] = bfs(y.w);
      af1[s] = f;
    }
  }
  __syncthreads();   // qb_s/wv_s ready + stage(0) drained (barrier waits vmcnt)

  float p0[4] = {0.f, 0.f, 0.f, 0.f};
  float p1[4] = {0.f, 0.f, 0.f, 0.f};

  for (int i = 0; i < 32; ++i) {            // 32 h-tiles
    if (i < 31) {                           // stage tile i+1 (async, early)
      const char* src = wkb + (size_t)(i + 1) * 8192 + (size_t)t * 16;
      char* dst = &bsm[(i + 1) & 1][w * 1024];
      gload16(src, dst);
      gload16(src + 4096, dst + 4096);
    }
    const char* buf = bsm[i & 1];
    f32x4 a0 = {0.f, 0.f, 0.f, 0.f};
    f32x4 a1 = {0.f, 0.f, 0.f, 0.f};
    #pragma unroll
    for (int s = 0; s < 8; ++s) {
      short8 bfr = *(const short8*)(buf + s * 1024 + l * 16);
      a0 = __builtin_amdgcn_mfma_f32_16x16x32_bf16(af0[s], bfr, a0, 0, 0, 0);
      a1 = __builtin_amdgcn_mfma_f32_16x16x32_bf16(af1[s], bfr, a1, 0, 0, 0);
    }
    const int h = i * 16 + ll;
    const float qb = qb_s[h];
    const float wv = wv_s[h];
    #pragma unroll
    for (int r = 0; r < 4; ++r) {
      p0[r] += wv * tanhf_fast(a0[r] + qb);
      p1[r] += wv * tanhf_fast(a1[r] + qb);
    }
    __syncthreads();   // stage(i+1) drained; buf swap safe
  }

  // reduce over h within each 16-lane group (col dim of C/D)
  #pragma unroll
  for (int r = 0; r < 4; ++r) {
    #pragma unroll
    for (int off = 1; off <= 8; off <<= 1) {
      p0[r] += __shfl_xor(p0[r], off, 64);
      p1[r] += __shfl_xor(p1[r], off, 64);
    }
  }
  if (ll == 0) {
    #pragma unroll
    for (int r = 0; r < 4; ++r) {
      sc[w * 32 + lg * 4 + r]      = p0[r];
      sc[w * 32 + 16 + lg * 4 + r] = p1[r];
    }
  }
  __syncthreads();

  // masked softmax over K=128 (wv_b omitted: softmax shift-invariant)
  if (t < KK) sc[t] += (float)masks[bn * KK + t] * (-1e9f);
  __syncthreads();
  if (t < 64) {
    float a = fmaxf(sc[t], sc[t + 64]);
    #pragma unroll
    for (int off = 32; off >= 1; off >>= 1) a = fmaxf(a, __shfl_xor(a, off, 64));
    if (t == 0) red[0] = a;
  }
  __syncthreads();
  const float m = red[0];
  if (t < KK) sc[t] = expf(sc[t] - m);
  __syncthreads();
  if (t < 64) {
    float a = sc[t] + sc[t + 64];
    #pragma unroll
    for (int off = 32; off >= 1; off >>= 1) a += __shfl_xor(a, off, 64);
    if (t == 0) red[1] = a;
  }
  __syncthreads();
  const float inv = 1.f / red[1];
  if (t < KK) {
    float wgt = sc[t] * inv;
    sc[t] = wgt;
    out[BN * EE + (size_t)bn * KK + t] = wgt;   // attn_weight
  }
  __syncthreads();

  // attn_out[bn][e] = sum_k w[k]*keys[bn,k,e]; float4 over e, 4-way k-split
  {
    const float4* kb4 = (const float4*)(keys + (size_t)bn * KK * EE);
    const int kh = t >> 6, ln = t & 63;
    float4 acc = {0.f, 0.f, 0.f, 0.f};
    #pragma unroll 4
    for (int k = 0; k < 32; ++k) {
      const float wgt = sc[kh * 32 + k];
      float4 kv = kb4[(size_t)(kh * 32 + k) * 64 + ln];
      acc.x += wgt * kv.x; acc.y += wgt * kv.y;
      acc.z += wgt * kv.z; acc.w += wgt * kv.w;
    }
    po4[kh][ln] = acc;
  }
  __syncthreads();
  if (t < 64) {
    float4 a = po4[0][t], b = po4[1][t], c = po4[2][t], d = po4[3][t];
    float4 r;
    r.x = a.x + b.x + c.x + d.x;
    r.y = a.y + b.y + c.y + d.y;
    r.z = a.z + b.z + c.z + d.z;
    r.w = a.w + b.w + c.w + d.w;
    *(float4*)(out + (size_t)bn * EE + t * 4) = r;
  }
}

// ---------------------------------------------------------------------------
extern "C" void kernel_launch(void* const* d_in, const int* in_sizes, int n_in,
                              void* d_out, int out_size, void* d_ws, size_t ws_size,
                              hipStream_t stream) {
  const float* queries = (const float*)d_in[0];
  const float* keys    = (const float*)d_in[1];
  const int*   masks   = (const int*)d_in[2];
  // d_in[3] = num_neg (unused)
  const float* wk_w = (const float*)d_in[4];
  const float* wk_b = (const float*)d_in[5];
  const float* wq_w = (const float*)d_in[6];
  const float* wq_b = (const float*)d_in[7];
  const float* wv_w = (const float*)d_in[8];
  // d_in[9] = wv_b (softmax shift-invariant -> unused)

  float* out = (float*)d_out;
  float* qp  = (float*)d_ws;                                // 512*512 f32 = 1 MB
  unsigned short* wk_fr = (unsigned short*)(qp + BN * HH);  // 256 KB

  k_prep<<<128, 256, 0, stream>>>(wk_w, queries, wq_w, wq_b, wk_b, wk_fr, qp);
  k_fused<<<BN, 256, 0, stream>>>(keys, wk_fr, wv_w, qp, masks, out);
}

// Round 11
// 50.780 us; speedup vs baseline: 2.0911x; 1.1258x over previous
//
#include <hip/hip_runtime.h>
#include <hip/hip_bf16.h>

// Problem constants
#define B_  64
#define N1_ 8
#define KK  128
#define EE  256
#define HH  512
#define BN  (B_ * N1_)   // 512

typedef __attribute__((ext_vector_type(8))) short short8;   // bf16x8 MFMA frag
typedef __attribute__((ext_vector_type(4))) float f32x4;    // MFMA acc

__device__ __forceinline__ short bfs(float f) {
  __hip_bfloat16 h = __float2bfloat16(f);   // RNE
  return __builtin_bit_cast(short, h);
}

__device__ __forceinline__ float tanhf_fast(float x) {
  // tanh(x) = 1 - 2/(exp(2x)+1);  exp(2x) = exp2(2*log2e*x)
  float e2 = __builtin_amdgcn_exp2f(2.8853900817779268f * x);
  return 1.0f - 2.0f * __builtin_amdgcn_rcpf(e2 + 1.0f);
}

// ---------------------------------------------------------------------------
// k_prep:
//  blocks 0..63  -> rewrite wk_w (512x256 f32) into FRAGMENT-MAJOR bf16:
//     chunk ((ht*8+s)*64 + lane)[8] = wk[ht*16+(lane&15)][(lane>>4)*8+s*32 ..]
//  blocks 64..127 -> qproj MFMA (32 bn-groups x 2 h-halves):
//     qp[bn][h] = q.wq[h] + wq_b[h] + wk_b[h]
// MFMA frag [m89]: A row=lane&15, e=(lane>>4)*8+s*32; D col=lane&15,
// row=(lane>>4)*4+reg.
// ---------------------------------------------------------------------------
__global__ __launch_bounds__(256) void k_prep(
    const float* __restrict__ wk_w,
    const float* __restrict__ queries,
    const float* __restrict__ wq_w,
    const float* __restrict__ wq_b,
    const float* __restrict__ wk_b,
    unsigned short* __restrict__ wk_fr,
    float* __restrict__ qp) {
  const int bid = blockIdx.x, t = threadIdx.x;
  if (bid < 64) {
    const int g  = bid * 256 + t;           // chunk id 0..16383
    const int h  = g >> 5;
    const int e0 = (g & 31) * 8;
    float4 x = *(const float4*)(wk_w + (size_t)h * EE + e0);
    float4 y = *(const float4*)(wk_w + (size_t)h * EE + e0 + 4);
    short8 f;
    f[0] = bfs(x.x); f[1] = bfs(x.y); f[2] = bfs(x.z); f[3] = bfs(x.w);
    f[4] = bfs(y.x); f[5] = bfs(y.y); f[6] = bfs(y.z); f[7] = bfs(y.w);
    const int ht = h >> 4, hl = h & 15;
    const int s = e0 >> 5, lg = (e0 >> 3) & 3;
    const int chunk = (ht * 8 + s) * 64 + lg * 16 + hl;
    *(short8*)(wk_fr + (size_t)chunk * 8) = f;
  } else {
    const int w = t >> 6, l = t & 63, lg = l >> 4, ll = l & 15;
    const int g2 = bid - 64;                // 0..63
    const int bn0 = (g2 >> 1) * 16;         // 32 bn-groups
    const int ht0 = (g2 & 1) * 16;          // h-half (16 h-tiles)
    short8 af[8];
    {
      const float* qr = queries + (size_t)(bn0 + ll) * EE + lg * 8;
      #pragma unroll
      for (int s = 0; s < 8; ++s) {
        float4 x = *(const float4*)(qr + s * 32);
        float4 y = *(const float4*)(qr + s * 32 + 4);
        short8 f;
        f[0] = bfs(x.x); f[1] = bfs(x.y); f[2] = bfs(x.z); f[3] = bfs(x.w);
        f[4] = bfs(y.x); f[5] = bfs(y.y); f[6] = bfs(y.z); f[7] = bfs(y.w);
        af[s] = f;
      }
    }
    #pragma unroll
    for (int i = 0; i < 4; ++i) {
      const int ht = ht0 + w * 4 + i;
      const float* bp = wq_w + (size_t)(ht * 16 + ll) * EE + lg * 8;
      f32x4 a = {0.f, 0.f, 0.f, 0.f};
      #pragma unroll
      for (int s = 0; s < 8; ++s) {
        float4 x = *(const float4*)(bp + s * 32);
        float4 y = *(const float4*)(bp + s * 32 + 4);
        short8 f;
        f[0] = bfs(x.x); f[1] = bfs(x.y); f[2] = bfs(x.z); f[3] = bfs(x.w);
        f[4] = bfs(y.x); f[5] = bfs(y.y); f[6] = bfs(y.z); f[7] = bfs(y.w);
        a = __builtin_amdgcn_mfma_f32_16x16x32_bf16(af[s], f, a, 0, 0, 0);
      }
      const int h = ht * 16 + ll;
      const float add = wq_b[h] + wk_b[h];
      #pragma unroll
      for (int r = 0; r < 4; ++r)
        qp[(size_t)(bn0 + lg * 4 + r) * HH + h] = a[r] + add;
    }
  }
}

// ---------------------------------------------------------------------------
// k_fused: one block = one bn (128 key-rows). 4 waves x 32 rows (2 chains);
// every wave covers all 512 h; softmax + PV fused in-block.
// B path: fragment-major wk_fr -> VGPR double buffer, direct global loads
// (contiguous 1 KB wave-reads, L1/L2-resident). NO LDS for B, NO barriers
// in the main loop -> 8 waves/CU drift freely and cover each other's
// latency. sched_barrier(0) after each load group pins the issue point
// (prevents the round-9 sink-to-use failure); waitcnt stays compiler-managed.
// MFMA 16x16x32 C/D: col(h)=lane&15, row(key)=(lane>>4)*4+reg   [m89].
// ---------------------------------------------------------------------------
__global__ __launch_bounds__(256, 2) void k_fused(
    const float* __restrict__ keys,
    const unsigned short* __restrict__ wk_fr,
    const float* __restrict__ wv_w,
    const float* __restrict__ qp,
    const int* __restrict__ masks,
    float* __restrict__ out) {
  const int t  = threadIdx.x;
  const int w  = t >> 6;      // wave 0..3
  const int l  = t & 63;
  const int lg = l >> 4;      // lane group 0..3
  const int ll = l & 15;
  const int bn = blockIdx.x;
  const short8* wkf = (const short8*)wk_fr;

  __shared__ float qb_s[HH];
  __shared__ float wv_s[HH];
  __shared__ float sc[KK];
  __shared__ float red[2];
  __shared__ float4 po4[4][64];

  qb_s[t]       = qp[(size_t)bn * HH + t];
  qb_s[t + 256] = qp[(size_t)bn * HH + t + 256];
  wv_s[t]       = wv_w[t];
  wv_s[t + 256] = wv_w[t + 256];

  // this wave's 32 rows -> bf16 A-frags in regs (2 chains x 8 slots)
  short8 af0[8], af1[8];
  {
    const float* kp0 = keys + (size_t)(bn * KK + w * 32 + ll) * EE + lg * 8;
    const float* kp1 = kp0 + 16 * EE;
    #pragma unroll
    for (int s = 0; s < 8; ++s) {
      float4 x = *(const float4*)(kp0 + s * 32);
      float4 y = *(const float4*)(kp0 + s * 32 + 4);
      short8 f;
      f[0] = bfs(x.x); f[1] = bfs(x.y); f[2] = bfs(x.z); f[3] = bfs(x.w);
      f[4] = bfs(y.x); f[5] = bfs(y.y); f[6] = bfs(y.z); f[7] = bfs(y.w);
      af0[s] = f;
      x = *(const float4*)(kp1 + s * 32);
      y = *(const float4*)(kp1 + s * 32 + 4);
      f[0] = bfs(x.x); f[1] = bfs(x.y); f[2] = bfs(x.z); f[3] = bfs(x.w);
      f[4] = bfs(y.x); f[5] = bfs(y.y); f[6] = bfs(y.z); f[7] = bfs(y.w);
      af1[s] = f;
    }
  }
  __syncthreads();   // qb_s / wv_s ready

  float p0[4] = {0.f, 0.f, 0.f, 0.f};
  float p1[4] = {0.f, 0.f, 0.f, 0.f};
  short8 bA[8], bB[8];

#define LOADB(dst, ht) {                                                   \
    _Pragma("unroll") for (int s = 0; s < 8; ++s)                          \
      dst[s] = wkf[((ht) * 8 + s) * 64 + l]; }

#define COMPUTE(cur, ii) {                                                 \
    f32x4 a0 = {0.f, 0.f, 0.f, 0.f};                                       \
    f32x4 a1 = {0.f, 0.f, 0.f, 0.f};                                       \
    __builtin_amdgcn_s_setprio(1);                                         \
    _Pragma("unroll") for (int s = 0; s < 8; ++s) {                        \
      a0 = __builtin_amdgcn_mfma_f32_16x16x32_bf16(af0[s], cur[s], a0, 0, 0, 0); \
      a1 = __builtin_amdgcn_mfma_f32_16x16x32_bf16(af1[s], cur[s], a1, 0, 0, 0); } \
    __builtin_amdgcn_s_setprio(0);                                         \
    const int h = (ii) * 16 + ll;                                          \
    const float qb = qb_s[h];                                              \
    const float wv = wv_s[h];                                              \
    _Pragma("unroll") for (int r = 0; r < 4; ++r) {                        \
      p0[r] += wv * tanhf_fast(a0[r] + qb);                                \
      p1[r] += wv * tanhf_fast(a1[r] + qb); } }

  LOADB(bA, 0);
  __builtin_amdgcn_sched_barrier(0);
  #pragma unroll 1
  for (int i = 0; i < 32; i += 2) {
    LOADB(bB, i + 1);                      // issue early; waited at its use
    __builtin_amdgcn_sched_barrier(0);     // pin issue point (no sinking)
    COMPUTE(bA, i);
    if (i < 30) {
      LOADB(bA, i + 2);
      __builtin_amdgcn_sched_barrier(0);
    }
    COMPUTE(bB, i + 1);
  }
#undef COMPUTE
#undef LOADB

  // reduce over h within each 16-lane group (col dim of C/D)
  #pragma unroll
  for (int r = 0; r < 4; ++r) {
    #pragma unroll
    for (int off = 1; off <= 8; off <<= 1) {
      p0[r] += __shfl_xor(p0[r], off, 64);
      p1[r] += __shfl_xor(p1[r], off, 64);
    }
  }
  if (ll == 0) {
    #pragma unroll
    for (int r = 0; r < 4; ++r) {
      sc[w * 32 + lg * 4 + r]      = p0[r];
      sc[w * 32 + 16 + lg * 4 + r] = p1[r];
    }
  }
  __syncthreads();

  // masked softmax over K=128 (wv_b omitted: softmax shift-invariant)
  if (t < KK) sc[t] += (float)masks[bn * KK + t] * (-1e9f);
  __syncthreads();
  if (t < 64) {
    float a = fmaxf(sc[t], sc[t + 64]);
    #pragma unroll
    for (int off = 32; off >= 1; off >>= 1) a = fmaxf(a, __shfl_xor(a, off, 64));
    if (t == 0) red[0] = a;
  }
  __syncthreads();
  const float m = red[0];
  if (t < KK) sc[t] = expf(sc[t] - m);
  __syncthreads();
  if (t < 64) {
    float a = sc[t] + sc[t + 64];
    #pragma unroll
    for (int off = 32; off >= 1; off >>= 1) a += __shfl_xor(a, off, 64);
    if (t == 0) red[1] = a;
  }
  __syncthreads();
  const float inv = 1.f / red[1];
  if (t < KK) {
    float wgt = sc[t] * inv;
    sc[t] = wgt;
    out[BN * EE + (size_t)bn * KK + t] = wgt;   // attn_weight
  }
  __syncthreads();

  // attn_out[bn][e] = sum_k w[k]*keys[bn,k,e]; float4 over e, 4-way k-split
  {
    const float4* kb4 = (const float4*)(keys + (size_t)bn * KK * EE);
    const int kh = t >> 6, ln = t & 63;
    float4 acc = {0.f, 0.f, 0.f, 0.f};
    #pragma unroll 4
    for (int k = 0; k < 32; ++k) {
      const float wgt = sc[kh * 32 + k];
      float4 kv = kb4[(size_t)(kh * 32 + k) * 64 + ln];
      acc.x += wgt * kv.x; acc.y += wgt * kv.y;
      acc.z += wgt * kv.z; acc.w += wgt * kv.w;
    }
    po4[kh][ln] = acc;
  }
  __syncthreads();
  if (t < 64) {
    float4 a = po4[0][t], b = po4[1][t], c = po4[2][t], d = po4[3][t];
    float4 r;
    r.x = a.x + b.x + c.x + d.x;
    r.y = a.y + b.y + c.y + d.y;
    r.z = a.z + b.z + c.z + d.z;
    r.w = a.w + b.w + c.w + d.w;
    *(float4*)(out + (size_t)bn * EE + t * 4) = r;
  }
}

// ---------------------------------------------------------------------------
extern "C" void kernel_launch(void* const* d_in, const int* in_sizes, int n_in,
                              void* d_out, int out_size, void* d_ws, size_t ws_size,
                              hipStream_t stream) {
  const float* queries = (const float*)d_in[0];
  const float* keys    = (const float*)d_in[1];
  const int*   masks   = (const int*)d_in[2];
  // d_in[3] = num_neg (unused)
  const float* wk_w = (const float*)d_in[4];
  const float* wk_b = (const float*)d_in[5];
  const float* wq_w = (const float*)d_in[6];
  const float* wq_b = (const float*)d_in[7];
  const float* wv_w = (const float*)d_in[8];
  // d_in[9] = wv_b (softmax shift-invariant -> unused)

  float* out = (float*)d_out;
  float* qp  = (float*)d_ws;                                // 512*512 f32 = 1 MB
  unsigned short* wk_fr = (unsigned short*)(qp + BN * HH);  // 256 KB

  k_prep<<<128, 256, 0, stream>>>(wk_w, queries, wq_w, wq_b, wk_b, wk_fr, qp);
  k_fused<<<BN, 256, 0, stream>>>(keys, wk_fr, wv_w, qp, masks, out);
}